// Round 1
// baseline (58.407 us; speedup 1.0000x reference)
//
#include <hip/hip_runtime.h>
#include <cmath>

#define TPB   128                 // threads per block (2 waves); each thread owns 4 cols
#define TH    32                  // output rows per block tile
#define WID   512
#define HEI   512
#define NIMG  64
#define NTILE (HEI / TH)          // 16
#define NBLK  (NIMG * NTILE)      // 1024

struct GW { float w[7]; };

// One input-row stage: load row gy, horizontal 7-tap blur of the 4 fields
// (a=p+t, b=p-t, a^2, b^2) into ring slot SL; when IY>=6 finish one output
// row (vertical 7-tap from ring + SSIM math) and accumulate.
template <int SL>
__device__ __forceinline__ void ssim_stage(
    int IY, int oy0, int m, int c0, int clm, int clp,
    const float* __restrict__ pb, const float* __restrict__ tb,
    const float (&wtv)[7],
    float (&rA)[7][4], float (&rB)[7][4], float (&rS)[7][4], float (&rT)[7][4],
    float& acc)
{
    const int gy = oy0 - 3 + IY;
    float pa[12], ta[12];
    if (gy >= 0 && gy < HEI) {
        const float* pr = pb + (size_t)gy * WID;
        const float* tr = tb + (size_t)gy * WID;
        float4 v0 = *(const float4*)(pr + clm);
        float4 v1 = *(const float4*)(pr + c0);
        float4 v2 = *(const float4*)(pr + clp);
        float4 u0 = *(const float4*)(tr + clm);
        float4 u1 = *(const float4*)(tr + c0);
        float4 u2 = *(const float4*)(tr + clp);
        if (m == 0)       { v0 = make_float4(0.f,0.f,0.f,0.f); u0 = make_float4(0.f,0.f,0.f,0.f); }
        if (m == TPB - 1) { v2 = make_float4(0.f,0.f,0.f,0.f); u2 = make_float4(0.f,0.f,0.f,0.f); }
        pa[0]=v0.x; pa[1]=v0.y; pa[2]=v0.z; pa[3]=v0.w;
        pa[4]=v1.x; pa[5]=v1.y; pa[6]=v1.z; pa[7]=v1.w;
        pa[8]=v2.x; pa[9]=v2.y; pa[10]=v2.z; pa[11]=v2.w;
        ta[0]=u0.x; ta[1]=u0.y; ta[2]=u0.z; ta[3]=u0.w;
        ta[4]=u1.x; ta[5]=u1.y; ta[6]=u1.z; ta[7]=u1.w;
        ta[8]=u2.x; ta[9]=u2.y; ta[10]=u2.z; ta[11]=u2.w;
    } else {
#pragma unroll
        for (int k = 0; k < 12; ++k) { pa[k] = 0.f; ta[k] = 0.f; }
    }

    // window wv[k] = value at column (c0 - 3 + k); output col c uses wv[c..c+6]
    float wv[10];

    // field A = blur(p + t)
#pragma unroll
    for (int k = 0; k < 10; ++k) wv[k] = pa[k + 1] + ta[k + 1];
#pragma unroll
    for (int c = 0; c < 4; ++c) {
        float s = 0.f;
#pragma unroll
        for (int i = 0; i < 7; ++i) s = fmaf(wtv[i], wv[c + i], s);
        rA[SL][c] = s;
    }
    // field S = blur((p + t)^2)
#pragma unroll
    for (int k = 0; k < 10; ++k) wv[k] = wv[k] * wv[k];
#pragma unroll
    for (int c = 0; c < 4; ++c) {
        float s = 0.f;
#pragma unroll
        for (int i = 0; i < 7; ++i) s = fmaf(wtv[i], wv[c + i], s);
        rS[SL][c] = s;
    }
    // field B = blur(p - t)
#pragma unroll
    for (int k = 0; k < 10; ++k) wv[k] = pa[k + 1] - ta[k + 1];
#pragma unroll
    for (int c = 0; c < 4; ++c) {
        float s = 0.f;
#pragma unroll
        for (int i = 0; i < 7; ++i) s = fmaf(wtv[i], wv[c + i], s);
        rB[SL][c] = s;
    }
    // field T = blur((p - t)^2)
#pragma unroll
    for (int k = 0; k < 10; ++k) wv[k] = wv[k] * wv[k];
#pragma unroll
    for (int c = 0; c < 4; ++c) {
        float s = 0.f;
#pragma unroll
        for (int i = 0; i < 7; ++i) s = fmaf(wtv[i], wv[c + i], s);
        rT[SL][c] = s;
    }

    if (IY >= 6) {
        const float C1 = 1e-4f, C2 = 9e-4f;
#pragma unroll
        for (int c = 0; c < 4; ++c) {
            float vA = 0.f, vB = 0.f, vS = 0.f, vT = 0.f;
#pragma unroll
            for (int j = 0; j < 7; ++j) {
                const int sl = (SL + 1 + j) % 7;   // compile-time
                vA = fmaf(wtv[j], rA[sl][c], vA);
                vB = fmaf(wtv[j], rB[sl][c], vB);
                vS = fmaf(wtv[j], rS[sl][c], vS);
                vT = fmaf(wtv[j], rT[sl][c], vT);
            }
            const float A2 = vA * vA, B2 = vB * vB;
            const float muct2 = 0.5f * (A2 - B2);   // 2*mu_p*mu_t
            const float muss  = 0.5f * (A2 + B2);   // mu_p^2 + mu_t^2
            const float ptb2  = 0.5f * (vS - vT);   // 2*blur(p*t)
            const float ssb   = 0.5f * (vS + vT);   // blur(p^2 + t^2)
            const float num = (muct2 + C1) * (ptb2 - muct2 + C2);
            const float den = (muss + C1) * (ssb - muss + C2);
            acc += num * __builtin_amdgcn_rcpf(den);
        }
    }
}

__global__ __launch_bounds__(TPB, 2)
void ssim_main_k(const float* __restrict__ pred,
                 const float* __restrict__ targ,
                 float* __restrict__ partial,   // NBLK floats (d_ws), or null
                 float* __restrict__ outacc,    // fallback atomic accumulator
                 GW gw)
{
    const int m    = threadIdx.x;
    const int bid  = blockIdx.x;
    const int img  = bid >> 4;            // NTILE == 16
    const int tile = bid & (NTILE - 1);
    const int oy0  = tile * TH;

    const float wtv[7] = { gw.w[0], gw.w[1], gw.w[2], gw.w[3], gw.w[4], gw.w[5], gw.w[6] };

    const size_t ioff = (size_t)img * (WID * HEI);
    const float* pb = pred + ioff;
    const float* tb = targ + ioff;

    const int c0  = 4 * m;
    const int clm = (m == 0) ? 0 : (c0 - 4);          // clamped (value zeroed)
    const int clp = (m == TPB - 1) ? c0 : (c0 + 4);   // clamped (value zeroed)

    float rA[7][4], rB[7][4], rS[7][4], rT[7][4];
    float acc = 0.f;

    // 38 input rows = 5*7 + 3; unroll in groups of 7 so ring slot == IY % 7 is static
    for (int it = 0; it < 5; ++it) {
        const int base = it * 7;
        ssim_stage<0>(base + 0, oy0, m, c0, clm, clp, pb, tb, wtv, rA, rB, rS, rT, acc);
        ssim_stage<1>(base + 1, oy0, m, c0, clm, clp, pb, tb, wtv, rA, rB, rS, rT, acc);
        ssim_stage<2>(base + 2, oy0, m, c0, clm, clp, pb, tb, wtv, rA, rB, rS, rT, acc);
        ssim_stage<3>(base + 3, oy0, m, c0, clm, clp, pb, tb, wtv, rA, rB, rS, rT, acc);
        ssim_stage<4>(base + 4, oy0, m, c0, clm, clp, pb, tb, wtv, rA, rB, rS, rT, acc);
        ssim_stage<5>(base + 5, oy0, m, c0, clm, clp, pb, tb, wtv, rA, rB, rS, rT, acc);
        ssim_stage<6>(base + 6, oy0, m, c0, clm, clp, pb, tb, wtv, rA, rB, rS, rT, acc);
    }
    ssim_stage<0>(35, oy0, m, c0, clm, clp, pb, tb, wtv, rA, rB, rS, rT, acc);
    ssim_stage<1>(36, oy0, m, c0, clm, clp, pb, tb, wtv, rA, rB, rS, rT, acc);
    ssim_stage<2>(37, oy0, m, c0, clm, clp, pb, tb, wtv, rA, rB, rS, rT, acc);

    // block reduction: wave shfl tree, then cross-wave via LDS
#pragma unroll
    for (int off = 32; off > 0; off >>= 1)
        acc += __shfl_down(acc, off, 64);
    __shared__ float wpart[TPB / 64];
    if ((m & 63) == 0) wpart[m >> 6] = acc;
    __syncthreads();
    if (m == 0) {
        const float tot = wpart[0] + wpart[1];
        if (partial) partial[bid] = tot;
        else atomicAdd(outacc, tot);
    }
}

__global__ void ssim_finalize_k(const float* __restrict__ partial,
                                float* __restrict__ out, int usews)
{
    const float invN = 1.0f / (float)((size_t)NIMG * WID * HEI);
    if (usews) {
        float s = 0.f;
        for (int i = threadIdx.x; i < NBLK; i += 256) s += partial[i];
#pragma unroll
        for (int off = 32; off > 0; off >>= 1) s += __shfl_down(s, off, 64);
        __shared__ float wp[4];
        if ((threadIdx.x & 63) == 0) wp[threadIdx.x >> 6] = s;
        __syncthreads();
        if (threadIdx.x == 0) out[0] = 1.0f - (wp[0] + wp[1] + wp[2] + wp[3]) * invN;
    } else {
        if (threadIdx.x == 0) out[0] = 1.0f - out[0] * invN;
    }
}

extern "C" void kernel_launch(void* const* d_in, const int* in_sizes, int n_in,
                              void* d_out, int out_size, void* d_ws, size_t ws_size,
                              hipStream_t stream)
{
    const float* pred = (const float*)d_in[0];
    const float* targ = (const float*)d_in[1];
    float* out = (float*)d_out;

    GW gw;
    {
        double g[7], s = 0.0;
        for (int i = 0; i < 7; ++i) {
            const double c = (double)(i - 3);
            g[i] = exp(-c * c / (2.0 * 1.5 * 1.5));
            s += g[i];
        }
        for (int i = 0; i < 7; ++i) gw.w[i] = (float)(g[i] / s);
    }

    const bool usews = (ws_size >= NBLK * sizeof(float));
    float* partial = usews ? (float*)d_ws : nullptr;
    if (!usews) hipMemsetAsync(d_out, 0, sizeof(float), stream);

    ssim_main_k<<<NBLK, TPB, 0, stream>>>(pred, targ, partial, out, gw);
    ssim_finalize_k<<<1, 256, 0, stream>>>(partial, out, usews ? 1 : 0);
}